// Round 1
// baseline (408.190 us; speedup 1.0000x reference)
//
#include <hip/hip_runtime.h>
#include <hip/hip_bf16.h>

#define S_LEN 4096
#define D_EMB 768
#define NH    12
#define HD    64
#define DQKV  2304
#define DFF   3072

typedef __attribute__((ext_vector_type(4))) short short4v;
typedef __attribute__((ext_vector_type(8))) short short8v;
typedef __attribute__((ext_vector_type(4))) float float4v;

static __device__ __forceinline__ float4v mfma16(short4v a, short4v b, float4v c) {
  return __builtin_amdgcn_mfma_f32_16x16x16bf16_1k(a, b, c, 0, 0, 0);
}

// ---------------- LayerNorm: fp32 in -> bf16 out, one block per row ----------------
__global__ __launch_bounds__(256) void ln_kernel(const float* __restrict__ x,
    const float* __restrict__ g, const float* __restrict__ b,
    __hip_bfloat16* __restrict__ out)
{
  int row = blockIdx.x;
  int tid = threadIdx.x;
  const float* xr = x + (size_t)row * D_EMB;
  float v0 = xr[tid], v1 = xr[tid + 256], v2 = xr[tid + 512];
  float s  = v0 + v1 + v2;
  float sq = v0 * v0 + v1 * v1 + v2 * v2;
  #pragma unroll
  for (int off = 32; off >= 1; off >>= 1) {
    s  += __shfl_xor(s, off);
    sq += __shfl_xor(sq, off);
  }
  __shared__ float ss[4], ssq[4];
  if ((tid & 63) == 0) { ss[tid >> 6] = s; ssq[tid >> 6] = sq; }
  __syncthreads();
  s  = ss[0] + ss[1] + ss[2] + ss[3];
  sq = ssq[0] + ssq[1] + ssq[2] + ssq[3];
  float mean = s * (1.0f / D_EMB);
  float var  = sq * (1.0f / D_EMB) - mean * mean;
  float rstd = rsqrtf(var + 1e-5f);
  __hip_bfloat16* orow = out + (size_t)row * D_EMB;
  orow[tid]       = __float2bfloat16((v0 - mean) * rstd * g[tid]       + b[tid]);
  orow[tid + 256] = __float2bfloat16((v1 - mean) * rstd * g[tid + 256] + b[tid + 256]);
  orow[tid + 512] = __float2bfloat16((v2 - mean) * rstd * g[tid + 512] + b[tid + 512]);
}

// ---------------- fp32 [K][N] -> bf16 [N][K] tiled transpose ----------------
__global__ __launch_bounds__(256) void transpose_bf16_kernel(const float* __restrict__ in,
    __hip_bfloat16* __restrict__ out, int K, int N)
{
  __shared__ float t[32][33];
  int nb = N >> 5;
  int bn = blockIdx.x % nb, bk = blockIdx.x / nb;
  int tx = threadIdx.x & 31, ty = threadIdx.x >> 5;
  #pragma unroll
  for (int i = 0; i < 4; i++)
    t[ty + 8 * i][tx] = in[(size_t)(bk * 32 + ty + 8 * i) * N + bn * 32 + tx];
  __syncthreads();
  #pragma unroll
  for (int i = 0; i < 4; i++)
    out[(size_t)(bn * 32 + ty + 8 * i) * K + bk * 32 + tx] = __float2bfloat16(t[tx][ty + 8 * i]);
}

// ---------------- GEMM: C = A[M,K] * Bt[N,K]^T + bias, epilogue variants ----------------
// EPI 0: +bias -> bf16   EPI 1: +bias, GELU(exact) -> bf16   EPI 2: +bias +resid -> fp32
template<int EPI>
__global__ __launch_bounds__(256) void gemm_kernel(
    const __hip_bfloat16* __restrict__ A,
    const __hip_bfloat16* __restrict__ Bt,
    const float* __restrict__ bias,
    const float* __restrict__ resid,
    void* __restrict__ Cout,
    int M, int N, int K)
{
  __shared__ __hip_bfloat16 Asm[128][40];
  __shared__ __hip_bfloat16 Bsm[128][40];
  int nb = N >> 7;
  int bx = blockIdx.x % nb, by = blockIdx.x / nb;
  int m0 = by << 7, n0 = bx << 7;
  int tid = threadIdx.x;
  int lane = tid & 63, lg = lane >> 4, li = lane & 15;
  int w = tid >> 6, wr = w >> 1, wc = w & 1;
  int srow = tid >> 1, sc = (tid & 1) << 4;

  float4v acc[4][4];
  #pragma unroll
  for (int i = 0; i < 4; i++)
    #pragma unroll
    for (int j = 0; j < 4; j++) {
      float4v z = {0.f, 0.f, 0.f, 0.f};
      acc[i][j] = z;
    }

  const __hip_bfloat16* aRow = A  + (size_t)(m0 + srow) * K + sc;
  const __hip_bfloat16* bRow = Bt + (size_t)(n0 + srow) * K + sc;

  for (int kt = 0; kt < K; kt += 32) {
    __syncthreads();
    short8v a0 = *(const short8v*)(aRow + kt);
    short8v a1 = *(const short8v*)(aRow + kt + 8);
    short8v b0 = *(const short8v*)(bRow + kt);
    short8v b1 = *(const short8v*)(bRow + kt + 8);
    *(short8v*)(&Asm[srow][sc])     = a0;
    *(short8v*)(&Asm[srow][sc + 8]) = a1;
    *(short8v*)(&Bsm[srow][sc])     = b0;
    *(short8v*)(&Bsm[srow][sc + 8]) = b1;
    __syncthreads();
    #pragma unroll
    for (int kk = 0; kk < 2; kk++) {
      short4v af[4], bf[4];
      #pragma unroll
      for (int f = 0; f < 4; f++) {
        af[f] = *(const short4v*)(&Asm[wr * 64 + f * 16 + li][kk * 16 + 4 * lg]);
        bf[f] = *(const short4v*)(&Bsm[wc * 64 + f * 16 + li][kk * 16 + 4 * lg]);
      }
      #pragma unroll
      for (int fr = 0; fr < 4; fr++)
        #pragma unroll
        for (int fc = 0; fc < 4; fc++)
          acc[fr][fc] = mfma16(af[fr], bf[fc], acc[fr][fc]);
    }
  }

  #pragma unroll
  for (int fr = 0; fr < 4; fr++) {
    int row = m0 + wr * 64 + fr * 16 + lg * 4;
    #pragma unroll
    for (int fc = 0; fc < 4; fc++) {
      int col = n0 + wc * 64 + fc * 16 + li;
      float bv = bias[col];
      #pragma unroll
      for (int r = 0; r < 4; r++) {
        float v = acc[fr][fc][r] + bv;
        size_t idx = (size_t)(row + r) * N + col;
        if (EPI == 1) {
          v = 0.5f * v * (1.0f + erff(v * 0.70710678118654752f));
          ((__hip_bfloat16*)Cout)[idx] = __float2bfloat16(v);
        } else if (EPI == 2) {
          ((float*)Cout)[idx] = v + resid[idx];
        } else {
          ((__hip_bfloat16*)Cout)[idx] = __float2bfloat16(v);
        }
      }
    }
  }
}

// ---------------- causal flash attention ----------------
// kqv: [4096][2304] bf16, order (k|q|v). y: [4096][768] bf16.
// One block per (head, q-block of 64). 4 waves, each owns 16 q-rows.
__global__ __launch_bounds__(256) void attn_kernel(const __hip_bfloat16* __restrict__ kqv,
                                                   __hip_bfloat16* __restrict__ y)
{
  __shared__ __hip_bfloat16 Ksm[64][72];   // [kv][d]
  __shared__ __hip_bfloat16 Vtsm[64][72];  // [d][kv]
  __shared__ __hip_bfloat16 Psm[4][16][72];// per wave [qrow][kv]
  int h  = blockIdx.x % NH;
  int qb = 63 - (blockIdx.x / NH);  // heavy blocks first
  int tid = threadIdx.x;
  int w = tid >> 6, lane = tid & 63, lg = lane >> 4, li = lane & 15;

  // Q fragments: rows qb*64 + w*16 + li, k = kk*16 + 4*lg + j
  short4v q[4];
  {
    const __hip_bfloat16* qp = kqv + (size_t)(qb * 64 + w * 16 + li) * DQKV + D_EMB + h * HD + 4 * lg;
    #pragma unroll
    for (int kk = 0; kk < 4; kk++) q[kk] = *(const short4v*)(qp + kk * 16);
  }

  float m[4]    = {-1e30f, -1e30f, -1e30f, -1e30f};
  float lsum[4] = {0.f, 0.f, 0.f, 0.f};
  float4v o[4];
  #pragma unroll
  for (int fc = 0; fc < 4; fc++) { float4v z = {0.f,0.f,0.f,0.f}; o[fc] = z; }

  int srow = tid >> 2, sc0 = (tid & 3) << 4;

  for (int kb = 0; kb <= qb; kb++) {
    __syncthreads();
    {
      const __hip_bfloat16* kp = kqv + (size_t)(kb * 64 + srow) * DQKV + h * HD + sc0;
      const __hip_bfloat16* vp = kqv + (size_t)(kb * 64 + srow) * DQKV + 2 * D_EMB + h * HD + sc0;
      short8v k0 = *(const short8v*)(kp);
      short8v k1 = *(const short8v*)(kp + 8);
      short8v v0 = *(const short8v*)(vp);
      short8v v1 = *(const short8v*)(vp + 8);
      *(short8v*)(&Ksm[srow][sc0])     = k0;
      *(short8v*)(&Ksm[srow][sc0 + 8]) = k1;
      #pragma unroll
      for (int j = 0; j < 8; j++) {
        *(short*)(&Vtsm[sc0 + j][srow])     = v0[j];
        *(short*)(&Vtsm[sc0 + 8 + j][srow]) = v1[j];
      }
    }
    __syncthreads();

    // S = Q K^T
    float4v s[4];
    #pragma unroll
    for (int fc = 0; fc < 4; fc++) { float4v z = {0.f,0.f,0.f,0.f}; s[fc] = z; }
    #pragma unroll
    for (int kk = 0; kk < 4; kk++) {
      #pragma unroll
      for (int fc = 0; fc < 4; fc++) {
        short4v bk = *(const short4v*)(&Ksm[fc * 16 + li][kk * 16 + 4 * lg]);
        s[fc] = mfma16(q[kk], bk, s[fc]);
      }
    }

    // online softmax (rows live in 16-lane groups: row = w*16 + lg*4 + r, col = fc*16 + li)
    bool diag = (kb == qb);
    #pragma unroll
    for (int r = 0; r < 4; r++) {
      int row_local = w * 16 + lg * 4 + r;
      float sv[4];
      float mx = -1e30f;
      #pragma unroll
      for (int fc = 0; fc < 4; fc++) {
        float v = s[fc][r] * 0.125f;
        if (diag && (fc * 16 + li) > row_local) v = -1e30f;
        sv[fc] = v;
        mx = fmaxf(mx, v);
      }
      mx = fmaxf(mx, __shfl_xor(mx, 1));
      mx = fmaxf(mx, __shfl_xor(mx, 2));
      mx = fmaxf(mx, __shfl_xor(mx, 4));
      mx = fmaxf(mx, __shfl_xor(mx, 8));
      float mn    = fmaxf(m[r], mx);
      float alpha = __expf(m[r] - mn);
      float rs = 0.f;
      #pragma unroll
      for (int fc = 0; fc < 4; fc++) {
        float p = __expf(sv[fc] - mn);
        s[fc][r] = p;
        rs += p;
      }
      rs += __shfl_xor(rs, 1);
      rs += __shfl_xor(rs, 2);
      rs += __shfl_xor(rs, 4);
      rs += __shfl_xor(rs, 8);
      lsum[r] = lsum[r] * alpha + rs;
      m[r] = mn;
      #pragma unroll
      for (int fc = 0; fc < 4; fc++) o[fc][r] *= alpha;
    }

    // P (C-layout) -> LDS -> A-layout
    #pragma unroll
    for (int fc = 0; fc < 4; fc++)
      #pragma unroll
      for (int r = 0; r < 4; r++)
        Psm[w][lg * 4 + r][fc * 16 + li] = __float2bfloat16(s[fc][r]);

    // O += P V
    #pragma unroll
    for (int kk = 0; kk < 4; kk++) {
      short4v ap = *(const short4v*)(&Psm[w][li][kk * 16 + 4 * lg]);
      #pragma unroll
      for (int fc = 0; fc < 4; fc++) {
        short4v bv = *(const short4v*)(&Vtsm[fc * 16 + li][kk * 16 + 4 * lg]);
        o[fc] = mfma16(ap, bv, o[fc]);
      }
    }
  }

  #pragma unroll
  for (int fc = 0; fc < 4; fc++) {
    int col = h * HD + fc * 16 + li;
    #pragma unroll
    for (int r = 0; r < 4; r++) {
      int row = qb * 64 + w * 16 + lg * 4 + r;
      y[(size_t)row * D_EMB + col] = __float2bfloat16(o[fc][r] / lsum[r]);
    }
  }
}

// ---------------- launch ----------------
extern "C" void kernel_launch(void* const* d_in, const int* in_sizes, int n_in,
                              void* d_out, int out_size, void* d_ws, size_t ws_size,
                              hipStream_t stream)
{
  const float* x      = (const float*)d_in[0];
  const float* w_qkv  = (const float*)d_in[1];
  const float* b_qkv  = (const float*)d_in[2];
  const float* w_proj = (const float*)d_in[3];
  const float* b_proj = (const float*)d_in[4];
  const float* w_fc1  = (const float*)d_in[5];
  const float* b_fc1  = (const float*)d_in[6];
  const float* w_fc2  = (const float*)d_in[7];
  const float* b_fc2  = (const float*)d_in[8];
  const float* ln1_g  = (const float*)d_in[9];
  const float* ln1_b  = (const float*)d_in[10];
  const float* ln2_g  = (const float*)d_in[11];
  const float* ln2_b  = (const float*)d_in[12];

  char* ws = (char*)d_ws;
  size_t off = 0;
  __hip_bfloat16* wqkvT = (__hip_bfloat16*)(ws + off); off += (size_t)DQKV * D_EMB * 2;   // [2304][768]
  __hip_bfloat16* wprojT= (__hip_bfloat16*)(ws + off); off += (size_t)D_EMB * D_EMB * 2;  // [768][768]
  __hip_bfloat16* wfc1T = (__hip_bfloat16*)(ws + off); off += (size_t)DFF * D_EMB * 2;    // [3072][768]
  __hip_bfloat16* wfc2T = (__hip_bfloat16*)(ws + off); off += (size_t)D_EMB * DFF * 2;    // [768][3072]
  __hip_bfloat16* lnbuf = (__hip_bfloat16*)(ws + off); off += (size_t)S_LEN * D_EMB * 2;  // [4096][768]
  __hip_bfloat16* kqv   = (__hip_bfloat16*)(ws + off);                                    // [4096][2304]
  __hip_bfloat16* hbuf  = kqv;                         off += (size_t)S_LEN * DQKV * 2;   // h aliases kqv+y
  __hip_bfloat16* ybuf  = (__hip_bfloat16*)(ws + off); off += (size_t)S_LEN * D_EMB * 2;  // [4096][768]
  float*          x1    = (float*)(ws + off);          off += (size_t)S_LEN * D_EMB * 4;  // [4096][768]
  (void)ws_size; (void)in_sizes; (void)n_in; (void)out_size;

  // weight transposes fp32[K][N] -> bf16[N][K]
  transpose_bf16_kernel<<<dim3((DQKV/32)*(D_EMB/32)), dim3(256), 0, stream>>>(w_qkv,  wqkvT, D_EMB, DQKV);
  transpose_bf16_kernel<<<dim3((D_EMB/32)*(D_EMB/32)), dim3(256), 0, stream>>>(w_proj, wprojT, D_EMB, D_EMB);
  transpose_bf16_kernel<<<dim3((DFF/32)*(D_EMB/32)),   dim3(256), 0, stream>>>(w_fc1,  wfc1T, D_EMB, DFF);
  transpose_bf16_kernel<<<dim3((D_EMB/32)*(DFF/32)),   dim3(256), 0, stream>>>(w_fc2,  wfc2T, DFF, D_EMB);

  // ln1
  ln_kernel<<<dim3(S_LEN), dim3(256), 0, stream>>>(x, ln1_g, ln1_b, lnbuf);
  // kqv = ln1 @ w_qkv + b_qkv
  gemm_kernel<0><<<dim3((DQKV/128)*(S_LEN/128)), dim3(256), 0, stream>>>(
      lnbuf, wqkvT, b_qkv, nullptr, kqv, S_LEN, DQKV, D_EMB);
  // attention
  attn_kernel<<<dim3(NH * (S_LEN/64)), dim3(256), 0, stream>>>(kqv, ybuf);
  // x1 = x + y @ w_proj + b_proj
  gemm_kernel<2><<<dim3((D_EMB/128)*(S_LEN/128)), dim3(256), 0, stream>>>(
      ybuf, wprojT, b_proj, x, x1, S_LEN, D_EMB, D_EMB);
  // ln2
  ln_kernel<<<dim3(S_LEN), dim3(256), 0, stream>>>(x1, ln2_g, ln2_b, lnbuf);
  // h = gelu(ln2 @ w_fc1 + b_fc1)
  gemm_kernel<1><<<dim3((DFF/128)*(S_LEN/128)), dim3(256), 0, stream>>>(
      lnbuf, wfc1T, b_fc1, nullptr, hbuf, S_LEN, DFF, D_EMB);
  // out = x1 + h @ w_fc2 + b_fc2
  gemm_kernel<2><<<dim3((D_EMB/128)*(S_LEN/128)), dim3(256), 0, stream>>>(
      hbuf, wfc2T, b_fc2, x1, (float*)d_out, S_LEN, D_EMB, DFF);
}

// Round 2
// 328.995 us; speedup vs baseline: 1.2407x; 1.2407x over previous
//
#include <hip/hip_runtime.h>
#include <hip/hip_bf16.h>

#define S_LEN 4096
#define D_EMB 768
#define NH    12
#define HD    64
#define DQKV  2304
#define DFF   3072

typedef __attribute__((ext_vector_type(4))) short short4v;
typedef __attribute__((ext_vector_type(8))) short short8v;
typedef __attribute__((ext_vector_type(4))) float float4v;

static __device__ __forceinline__ float4v mfma16(short4v a, short4v b, float4v c) {
  return __builtin_amdgcn_mfma_f32_16x16x16bf16_1k(a, b, c, 0, 0, 0);
}

static __device__ __forceinline__ short bf16bits(float f) {
  __hip_bfloat16 h = __float2bfloat16(f);
  return *reinterpret_cast<short*>(&h);
}

// ---------------- LayerNorm: fp32 in -> bf16 out, one block per row ----------------
__global__ __launch_bounds__(256) void ln_kernel(const float* __restrict__ x,
    const float* __restrict__ g, const float* __restrict__ b,
    __hip_bfloat16* __restrict__ out)
{
  int row = blockIdx.x;
  int tid = threadIdx.x;
  const float* xr = x + (size_t)row * D_EMB;
  float v0 = xr[tid], v1 = xr[tid + 256], v2 = xr[tid + 512];
  float s  = v0 + v1 + v2;
  float sq = v0 * v0 + v1 * v1 + v2 * v2;
  #pragma unroll
  for (int off = 32; off >= 1; off >>= 1) {
    s  += __shfl_xor(s, off);
    sq += __shfl_xor(sq, off);
  }
  __shared__ float ss[4], ssq[4];
  if ((tid & 63) == 0) { ss[tid >> 6] = s; ssq[tid >> 6] = sq; }
  __syncthreads();
  s  = ss[0] + ss[1] + ss[2] + ss[3];
  sq = ssq[0] + ssq[1] + ssq[2] + ssq[3];
  float mean = s * (1.0f / D_EMB);
  float var  = sq * (1.0f / D_EMB) - mean * mean;
  float rstd = rsqrtf(var + 1e-5f);
  __hip_bfloat16* orow = out + (size_t)row * D_EMB;
  orow[tid]       = __float2bfloat16((v0 - mean) * rstd * g[tid]       + b[tid]);
  orow[tid + 256] = __float2bfloat16((v1 - mean) * rstd * g[tid + 256] + b[tid + 256]);
  orow[tid + 512] = __float2bfloat16((v2 - mean) * rstd * g[tid + 512] + b[tid + 512]);
}

// ---------------- fp32 [K][N] -> bf16 [N][K] tiled transpose ----------------
__global__ __launch_bounds__(256) void transpose_bf16_kernel(const float* __restrict__ in,
    __hip_bfloat16* __restrict__ out, int K, int N)
{
  __shared__ float t[32][33];
  int nb = N >> 5;
  int bn = blockIdx.x % nb, bk = blockIdx.x / nb;
  int tx = threadIdx.x & 31, ty = threadIdx.x >> 5;
  #pragma unroll
  for (int i = 0; i < 4; i++)
    t[ty + 8 * i][tx] = in[(size_t)(bk * 32 + ty + 8 * i) * N + bn * 32 + tx];
  __syncthreads();
  #pragma unroll
  for (int i = 0; i < 4; i++)
    out[(size_t)(bn * 32 + ty + 8 * i) * K + bk * 32 + tx] = __float2bfloat16(t[tx][ty + 8 * i]);
}

// ---------------- GEMM: C = A[M,K] * Bt[N,K]^T + bias, epilogue variants ----------------
// EPI 0: +bias -> bf16   EPI 1: +bias, GELU(exact) -> bf16   EPI 2: +bias +resid -> fp32
template<int EPI>
__global__ __launch_bounds__(256) void gemm_kernel(
    const __hip_bfloat16* __restrict__ A,
    const __hip_bfloat16* __restrict__ Bt,
    const float* __restrict__ bias,
    const float* __restrict__ resid,
    void* __restrict__ Cout,
    int M, int N, int K)
{
  __shared__ __hip_bfloat16 Asm[128][40];
  __shared__ __hip_bfloat16 Bsm[128][40];
  int nb = N >> 7;
  int bx = blockIdx.x % nb, by = blockIdx.x / nb;
  int m0 = by << 7, n0 = bx << 7;
  int tid = threadIdx.x;
  int lane = tid & 63, lg = lane >> 4, li = lane & 15;
  int w = tid >> 6, wr = w >> 1, wc = w & 1;
  int srow = tid >> 1, sc = (tid & 1) << 4;

  float4v acc[4][4];
  #pragma unroll
  for (int i = 0; i < 4; i++)
    #pragma unroll
    for (int j = 0; j < 4; j++) {
      float4v z = {0.f, 0.f, 0.f, 0.f};
      acc[i][j] = z;
    }

  const __hip_bfloat16* aRow = A  + (size_t)(m0 + srow) * K + sc;
  const __hip_bfloat16* bRow = Bt + (size_t)(n0 + srow) * K + sc;

  for (int kt = 0; kt < K; kt += 32) {
    __syncthreads();
    short8v a0 = *(const short8v*)(aRow + kt);
    short8v a1 = *(const short8v*)(aRow + kt + 8);
    short8v b0 = *(const short8v*)(bRow + kt);
    short8v b1 = *(const short8v*)(bRow + kt + 8);
    *(short8v*)(&Asm[srow][sc])     = a0;
    *(short8v*)(&Asm[srow][sc + 8]) = a1;
    *(short8v*)(&Bsm[srow][sc])     = b0;
    *(short8v*)(&Bsm[srow][sc + 8]) = b1;
    __syncthreads();
    #pragma unroll
    for (int kk = 0; kk < 2; kk++) {
      short4v af[4], bf[4];
      #pragma unroll
      for (int f = 0; f < 4; f++) {
        af[f] = *(const short4v*)(&Asm[wr * 64 + f * 16 + li][kk * 16 + 4 * lg]);
        bf[f] = *(const short4v*)(&Bsm[wc * 64 + f * 16 + li][kk * 16 + 4 * lg]);
      }
      #pragma unroll
      for (int fr = 0; fr < 4; fr++)
        #pragma unroll
        for (int fc = 0; fc < 4; fc++)
          acc[fr][fc] = mfma16(af[fr], bf[fc], acc[fr][fc]);
    }
  }

  #pragma unroll
  for (int fr = 0; fr < 4; fr++) {
    int row = m0 + wr * 64 + fr * 16 + lg * 4;
    #pragma unroll
    for (int fc = 0; fc < 4; fc++) {
      int col = n0 + wc * 64 + fc * 16 + li;
      float bv = bias[col];
      #pragma unroll
      for (int r = 0; r < 4; r++) {
        float v = acc[fr][fc][r] + bv;
        size_t idx = (size_t)(row + r) * N + col;
        if (EPI == 1) {
          v = 0.5f * v * (1.0f + erff(v * 0.70710678118654752f));
          ((__hip_bfloat16*)Cout)[idx] = __float2bfloat16(v);
        } else if (EPI == 2) {
          ((float*)Cout)[idx] = v + resid[idx];
        } else {
          ((__hip_bfloat16*)Cout)[idx] = __float2bfloat16(v);
        }
      }
    }
  }
}

// ---------------- causal flash attention (swapped-operand, in-register P) ----------------
// kqv: [4096][2304] bf16, order (k|q|v). y: [4096][768] bf16.
// One block per (head, q-block of 64). 4 waves, each wave owns 16 q-rows,
// lane li = one q-row; S^T = mfma(K, Q) so P lives in registers.
__global__ __launch_bounds__(256) void attn_kernel(const __hip_bfloat16* __restrict__ kqv,
                                                   __hip_bfloat16* __restrict__ y)
{
  __shared__ __hip_bfloat16 Ksm[64][72];   // [kv][d]
  __shared__ __hip_bfloat16 Vtsm[64][66];  // [d][kv], paired-b32 writes (<=2-way)
  int h  = blockIdx.x % NH;
  int qb = 63 - (blockIdx.x / NH);  // heavy blocks first
  int tid = threadIdx.x;
  int w = tid >> 6, lane = tid & 63, lg = lane >> 4, li = lane & 15;

  // Q as B-operand: lane li = q-col, k = kk*16 + 4*lg + j
  short4v q[4];
  {
    const __hip_bfloat16* qp = kqv + (size_t)(qb * 64 + w * 16 + li) * DQKV + D_EMB + h * HD + 4 * lg;
    #pragma unroll
    for (int kk = 0; kk < 4; kk++) q[kk] = *(const short4v*)(qp + kk * 16);
  }

  float m = -1e30f, lsum = 0.f;
  float4v o[4];  // O^T frags: lane holds q=li, d = fc*16 + 4*lg + r
  #pragma unroll
  for (int fc = 0; fc < 4; fc++) { float4v z = {0.f,0.f,0.f,0.f}; o[fc] = z; }

  // staging roles
  int krow = tid >> 2, kc = (tid & 3) << 4;       // K: row, 16-col group (2x short8)
  int vr = (tid >> 3) << 1, vc = (tid & 7) << 3;  // V: kv row-pair, 8-col group
  const __hip_bfloat16* kbase = kqv + h * HD;
  const __hip_bfloat16* vbase = kqv + 2 * D_EMB + h * HD;

  short8v kA, kB, vA, vB;
  {
    const __hip_bfloat16* kp = kbase + (size_t)krow * DQKV + kc;
    kA = *(const short8v*)kp;
    kB = *(const short8v*)(kp + 8);
    const __hip_bfloat16* vp = vbase + (size_t)vr * DQKV + vc;
    vA = *(const short8v*)vp;
    vB = *(const short8v*)(vp + DQKV);
  }

  for (int kb = 0; kb <= qb; kb++) {
    __syncthreads();
    *(short8v*)(&Ksm[krow][kc])     = kA;
    *(short8v*)(&Ksm[krow][kc + 8]) = kB;
    #pragma unroll
    for (int j = 0; j < 8; j++) {
      unsigned int pk = (unsigned int)(unsigned short)vA[j]
                      | ((unsigned int)(unsigned short)vB[j] << 16);
      *reinterpret_cast<unsigned int*>(&Vtsm[vc + j][vr]) = pk;
    }
    __syncthreads();

    if (kb < qb) {  // prefetch next tile; latency hides under compute
      const __hip_bfloat16* kp = kbase + (size_t)((kb + 1) * 64 + krow) * DQKV + kc;
      kA = *(const short8v*)kp;
      kB = *(const short8v*)(kp + 8);
      const __hip_bfloat16* vp = vbase + (size_t)((kb + 1) * 64 + vr) * DQKV + vc;
      vA = *(const short8v*)vp;
      vB = *(const short8v*)(vp + DQKV);
    }

    // S^T = K * Q^T : s[fc] covers kv = fc*16 + 4*lg + r, q = li
    float4v s[4];
    #pragma unroll
    for (int fc = 0; fc < 4; fc++) { float4v z = {0.f,0.f,0.f,0.f}; s[fc] = z; }
    #pragma unroll
    for (int kk = 0; kk < 4; kk++) {
      #pragma unroll
      for (int fc = 0; fc < 4; fc++) {
        short4v kf = *(const short4v*)(&Ksm[fc * 16 + li][kk * 16 + 4 * lg]);
        s[fc] = mfma16(kf, q[kk], s[fc]);
      }
    }

    // online softmax: lane owns one q-row; reduce across lg via xor 16/32
    bool diag = (kb == qb);
    float pmax = -1e30f;
    #pragma unroll
    for (int fc = 0; fc < 4; fc++) {
      #pragma unroll
      for (int r = 0; r < 4; r++) {
        float v = s[fc][r] * 0.125f;
        if (diag && (fc * 16 + 4 * lg + r) > (w * 16 + li)) v = -1e30f;
        s[fc][r] = v;
        pmax = fmaxf(pmax, v);
      }
    }
    pmax = fmaxf(pmax, __shfl_xor(pmax, 16));
    pmax = fmaxf(pmax, __shfl_xor(pmax, 32));
    float mn = fmaxf(m, pmax);
    float alpha = __expf(m - mn);
    float rs = 0.f;
    #pragma unroll
    for (int fc = 0; fc < 4; fc++) {
      #pragma unroll
      for (int r = 0; r < 4; r++) {
        float p = __expf(s[fc][r] - mn);
        s[fc][r] = p;
        rs += p;
      }
    }
    rs += __shfl_xor(rs, 16);
    rs += __shfl_xor(rs, 32);
    lsum = lsum * alpha + rs;
    m = mn;
    #pragma unroll
    for (int fc = 0; fc < 4; fc++) {
      #pragma unroll
      for (int r = 0; r < 4; r++) o[fc][r] *= alpha;
    }

    // P^T fragments (B-operand) come straight from registers
    short4v pb[4];
    #pragma unroll
    for (int kk = 0; kk < 4; kk++) {
      short4v t;
      #pragma unroll
      for (int r = 0; r < 4; r++) t[r] = bf16bits(s[kk][r]);
      pb[kk] = t;
    }

    // O^T += V^T * P^T
    #pragma unroll
    for (int kk = 0; kk < 4; kk++) {
      #pragma unroll
      for (int fc = 0; fc < 4; fc++) {
        short4v vf = *(const short4v*)(&Vtsm[fc * 16 + li][kk * 16 + 4 * lg]);
        o[fc] = mfma16(vf, pb[kk], o[fc]);
      }
    }
  }

  // epilogue: lane li -> q-row; d = fc*16 + 4*lg + r (r consecutive -> 8B stores)
  float inv = 1.0f / lsum;
  int qrow = qb * 64 + w * 16 + li;
  #pragma unroll
  for (int fc = 0; fc < 4; fc++) {
    short4v ov;
    #pragma unroll
    for (int r = 0; r < 4; r++) ov[r] = bf16bits(o[fc][r] * inv);
    *reinterpret_cast<short4v*>(y + (size_t)qrow * D_EMB + h * HD + fc * 16 + 4 * lg) = ov;
  }
}

// ---------------- launch ----------------
extern "C" void kernel_launch(void* const* d_in, const int* in_sizes, int n_in,
                              void* d_out, int out_size, void* d_ws, size_t ws_size,
                              hipStream_t stream)
{
  const float* x      = (const float*)d_in[0];
  const float* w_qkv  = (const float*)d_in[1];
  const float* b_qkv  = (const float*)d_in[2];
  const float* w_proj = (const float*)d_in[3];
  const float* b_proj = (const float*)d_in[4];
  const float* w_fc1  = (const float*)d_in[5];
  const float* b_fc1  = (const float*)d_in[6];
  const float* w_fc2  = (const float*)d_in[7];
  const float* b_fc2  = (const float*)d_in[8];
  const float* ln1_g  = (const float*)d_in[9];
  const float* ln1_b  = (const float*)d_in[10];
  const float* ln2_g  = (const float*)d_in[11];
  const float* ln2_b  = (const float*)d_in[12];

  char* ws = (char*)d_ws;
  size_t off = 0;
  __hip_bfloat16* wqkvT = (__hip_bfloat16*)(ws + off); off += (size_t)DQKV * D_EMB * 2;   // [2304][768]
  __hip_bfloat16* wprojT= (__hip_bfloat16*)(ws + off); off += (size_t)D_EMB * D_EMB * 2;  // [768][768]
  __hip_bfloat16* wfc1T = (__hip_bfloat16*)(ws + off); off += (size_t)DFF * D_EMB * 2;    // [3072][768]
  __hip_bfloat16* wfc2T = (__hip_bfloat16*)(ws + off); off += (size_t)D_EMB * DFF * 2;    // [768][3072]
  __hip_bfloat16* lnbuf = (__hip_bfloat16*)(ws + off); off += (size_t)S_LEN * D_EMB * 2;  // [4096][768]
  __hip_bfloat16* kqv   = (__hip_bfloat16*)(ws + off);                                    // [4096][2304]
  __hip_bfloat16* hbuf  = kqv;                         off += (size_t)S_LEN * DQKV * 2;   // h aliases kqv
  __hip_bfloat16* ybuf  = (__hip_bfloat16*)(ws + off); off += (size_t)S_LEN * D_EMB * 2;  // [4096][768]
  float*          x1    = (float*)(ws + off);          off += (size_t)S_LEN * D_EMB * 4;  // [4096][768]
  (void)ws_size; (void)in_sizes; (void)n_in; (void)out_size;

  // weight transposes fp32[K][N] -> bf16[N][K]
  transpose_bf16_kernel<<<dim3((DQKV/32)*(D_EMB/32)), dim3(256), 0, stream>>>(w_qkv,  wqkvT, D_EMB, DQKV);
  transpose_bf16_kernel<<<dim3((D_EMB/32)*(D_EMB/32)), dim3(256), 0, stream>>>(w_proj, wprojT, D_EMB, D_EMB);
  transpose_bf16_kernel<<<dim3((DFF/32)*(D_EMB/32)),   dim3(256), 0, stream>>>(w_fc1,  wfc1T, D_EMB, DFF);
  transpose_bf16_kernel<<<dim3((D_EMB/32)*(DFF/32)),   dim3(256), 0, stream>>>(w_fc2,  wfc2T, DFF, D_EMB);

  // ln1
  ln_kernel<<<dim3(S_LEN), dim3(256), 0, stream>>>(x, ln1_g, ln1_b, lnbuf);
  // kqv = ln1 @ w_qkv + b_qkv
  gemm_kernel<0><<<dim3((DQKV/128)*(S_LEN/128)), dim3(256), 0, stream>>>(
      lnbuf, wqkvT, b_qkv, nullptr, kqv, S_LEN, DQKV, D_EMB);
  // attention
  attn_kernel<<<dim3(NH * (S_LEN/64)), dim3(256), 0, stream>>>(kqv, ybuf);
  // x1 = x + y @ w_proj + b_proj
  gemm_kernel<2><<<dim3((D_EMB/128)*(S_LEN/128)), dim3(256), 0, stream>>>(
      ybuf, wprojT, b_proj, x, x1, S_LEN, D_EMB, D_EMB);
  // ln2
  ln_kernel<<<dim3(S_LEN), dim3(256), 0, stream>>>(x1, ln2_g, ln2_b, lnbuf);
  // h = gelu(ln2 @ w_fc1 + b_fc1)
  gemm_kernel<1><<<dim3((DFF/128)*(S_LEN/128)), dim3(256), 0, stream>>>(
      lnbuf, wfc1T, b_fc1, nullptr, hbuf, S_LEN, DFF, D_EMB);
  // out = x1 + h @ w_fc2 + b_fc2
  gemm_kernel<2><<<dim3((D_EMB/128)*(S_LEN/128)), dim3(256), 0, stream>>>(
      hbuf, wfc2T, b_fc2, x1, (float*)d_out, S_LEN, D_EMB, DFF);
}

// Round 3
// 255.156 us; speedup vs baseline: 1.5998x; 1.2894x over previous
//
#include <hip/hip_runtime.h>
#include <hip/hip_bf16.h>

#define S_LEN 4096
#define D_EMB 768
#define NH    12
#define HD    64
#define DQKV  2304
#define DFF   3072

typedef __attribute__((ext_vector_type(4))) short short4v;
typedef __attribute__((ext_vector_type(8))) short short8v;
typedef __attribute__((ext_vector_type(4))) float float4v;

static __device__ __forceinline__ float4v mfma16(short4v a, short4v b, float4v c) {
  return __builtin_amdgcn_mfma_f32_16x16x16bf16_1k(a, b, c, 0, 0, 0);
}

static __device__ __forceinline__ short bf16bits(float f) {
  __hip_bfloat16 h = __float2bfloat16(f);
  return *reinterpret_cast<short*>(&h);
}

// async global -> LDS, 16B per lane. LDS dest must be wave-uniform base + lane*16.
static __device__ __forceinline__ void gload16(const __hip_bfloat16* g, __hip_bfloat16* l) {
  __builtin_amdgcn_global_load_lds((const __attribute__((address_space(1))) void*)g,
                                   (__attribute__((address_space(3))) void*)l, 16, 0, 0);
}

// ---------------- LayerNorm: fp32 in -> bf16 out, one block per row ----------------
__global__ __launch_bounds__(256) void ln_kernel(const float* __restrict__ x,
    const float* __restrict__ g, const float* __restrict__ b,
    __hip_bfloat16* __restrict__ out)
{
  int row = blockIdx.x;
  int tid = threadIdx.x;
  const float* xr = x + (size_t)row * D_EMB;
  float v0 = xr[tid], v1 = xr[tid + 256], v2 = xr[tid + 512];
  float s  = v0 + v1 + v2;
  float sq = v0 * v0 + v1 * v1 + v2 * v2;
  #pragma unroll
  for (int off = 32; off >= 1; off >>= 1) {
    s  += __shfl_xor(s, off);
    sq += __shfl_xor(sq, off);
  }
  __shared__ float ss[4], ssq[4];
  if ((tid & 63) == 0) { ss[tid >> 6] = s; ssq[tid >> 6] = sq; }
  __syncthreads();
  s  = ss[0] + ss[1] + ss[2] + ss[3];
  sq = ssq[0] + ssq[1] + ssq[2] + ssq[3];
  float mean = s * (1.0f / D_EMB);
  float var  = sq * (1.0f / D_EMB) - mean * mean;
  float rstd = rsqrtf(var + 1e-5f);
  __hip_bfloat16* orow = out + (size_t)row * D_EMB;
  orow[tid]       = __float2bfloat16((v0 - mean) * rstd * g[tid]       + b[tid]);
  orow[tid + 256] = __float2bfloat16((v1 - mean) * rstd * g[tid + 256] + b[tid + 256]);
  orow[tid + 512] = __float2bfloat16((v2 - mean) * rstd * g[tid + 512] + b[tid + 512]);
}

// ---------------- fp32 [K][N] -> bf16 [N][K] tiled transpose ----------------
__global__ __launch_bounds__(256) void transpose_bf16_kernel(const float* __restrict__ in,
    __hip_bfloat16* __restrict__ out, int K, int N)
{
  __shared__ float t[32][33];
  int nb = N >> 5;
  int bn = blockIdx.x % nb, bk = blockIdx.x / nb;
  int tx = threadIdx.x & 31, ty = threadIdx.x >> 5;
  #pragma unroll
  for (int i = 0; i < 4; i++)
    t[ty + 8 * i][tx] = in[(size_t)(bk * 32 + ty + 8 * i) * N + bn * 32 + tx];
  __syncthreads();
  #pragma unroll
  for (int i = 0; i < 4; i++)
    out[(size_t)(bn * 32 + ty + 8 * i) * K + bk * 32 + tx] = __float2bfloat16(t[tx][ty + 8 * i]);
}

// ---------------- GEMM (m97 structure): C = A[M,K] * Bt[N,K]^T + bias ----------------
// 128x128 tile, BK=64, global_load_lds width=16, 16x16x32 MFMA, XOR chunk-swizzle.
// EPI 0: +bias -> bf16   EPI 1: +bias, GELU(exact) -> bf16   EPI 2: +bias +resid -> fp32
template<int EPI>
__global__ __launch_bounds__(256) void gemm_kernel(
    const __hip_bfloat16* __restrict__ A,
    const __hip_bfloat16* __restrict__ Bt,
    const float* __restrict__ bias,
    const float* __restrict__ resid,
    void* __restrict__ Cout,
    int M, int N, int K)
{
  __shared__ __hip_bfloat16 Asm[128 * 64];  // [row][64k] linear, swizzled content
  __shared__ __hip_bfloat16 Bsm[128 * 64];
  int nb = N >> 7;
  int bx = blockIdx.x % nb, by = blockIdx.x / nb;
  int m0 = by << 7, n0 = bx << 7;
  int tid = threadIdx.x;
  int lane = tid & 63, lg = lane >> 4, li = lane & 15;
  int w = tid >> 6, wr = w >> 1, wc = w & 1;

  // staging roles: row sr (0..31 per issue, +32 per issue), source chunk swizzled
  int sr  = tid >> 3;                 // 0..31
  int scn = (tid & 7) ^ (sr & 7);     // source chunk: dest chunk (tid&7) XOR row&7
  const __hip_bfloat16* aSrc = A  + (size_t)(m0 + sr) * K + scn * 8;
  const __hip_bfloat16* bSrc = Bt + (size_t)(n0 + sr) * K + scn * 8;
  __hip_bfloat16* aDst = Asm + tid * 8;   // +i*2048 elems per issue
  __hip_bfloat16* bDst = Bsm + tid * 8;
  const size_t rowStep = (size_t)32 * K;

  float4v acc[4][4];
  #pragma unroll
  for (int i = 0; i < 4; i++)
    #pragma unroll
    for (int j = 0; j < 4; j++) {
      float4v z = {0.f, 0.f, 0.f, 0.f};
      acc[i][j] = z;
    }

  int sw = li & 7;  // read-side row&7 (rows are f*16+li -> &7 == li&7)

  for (int kt = 0; kt < K; kt += 64) {
    #pragma unroll
    for (int i = 0; i < 4; i++) {
      gload16(aSrc + i * rowStep, aDst + i * 2048);
      gload16(bSrc + i * rowStep, bDst + i * 2048);
    }
    aSrc += 64; bSrc += 64;
    __syncthreads();   // drains vmcnt(0) then barrier: staged data visible to all
    #pragma unroll
    for (int kk = 0; kk < 2; kk++) {
      short8v af[4], bf[4];
      #pragma unroll
      for (int f = 0; f < 4; f++) {
        int ar = wr * 64 + f * 16 + li;
        int br = wc * 64 + f * 16 + li;
        int ch = ((kk << 2) | lg) ^ sw;
        af[f] = *(const short8v*)(Asm + ar * 64 + ch * 8);
        bf[f] = *(const short8v*)(Bsm + br * 64 + ch * 8);
      }
      #pragma unroll
      for (int fr = 0; fr < 4; fr++)
        #pragma unroll
        for (int fc = 0; fc < 4; fc++)
          acc[fr][fc] = __builtin_amdgcn_mfma_f32_16x16x32_bf16(af[fr], bf[fc], acc[fr][fc], 0, 0, 0);
    }
    __syncthreads();   // protect LDS before next overwrite
  }

  #pragma unroll
  for (int fr = 0; fr < 4; fr++) {
    int row = m0 + wr * 64 + fr * 16 + lg * 4;
    #pragma unroll
    for (int fc = 0; fc < 4; fc++) {
      int col = n0 + wc * 64 + fc * 16 + li;
      float bv = bias[col];
      #pragma unroll
      for (int r = 0; r < 4; r++) {
        float v = acc[fr][fc][r] + bv;
        size_t idx = (size_t)(row + r) * N + col;
        if (EPI == 1) {
          v = 0.5f * v * (1.0f + erff(v * 0.70710678118654752f));
          ((__hip_bfloat16*)Cout)[idx] = __float2bfloat16(v);
        } else if (EPI == 2) {
          ((float*)Cout)[idx] = v + resid[idx];
        } else {
          ((__hip_bfloat16*)Cout)[idx] = __float2bfloat16(v);
        }
      }
    }
  }
}

// ---------------- causal flash attention (swapped-operand, in-register P) ----------------
__global__ __launch_bounds__(256) void attn_kernel(const __hip_bfloat16* __restrict__ kqv,
                                                   __hip_bfloat16* __restrict__ y)
{
  __shared__ __hip_bfloat16 Ksm[64][72];   // [kv][d]
  __shared__ __hip_bfloat16 Vtsm[64][66];  // [d][kv], paired-b32 writes (<=2-way)
  int h  = blockIdx.x % NH;
  int qb = 63 - (blockIdx.x / NH);  // heavy blocks first
  int tid = threadIdx.x;
  int w = tid >> 6, lane = tid & 63, lg = lane >> 4, li = lane & 15;

  short4v q[4];
  {
    const __hip_bfloat16* qp = kqv + (size_t)(qb * 64 + w * 16 + li) * DQKV + D_EMB + h * HD + 4 * lg;
    #pragma unroll
    for (int kk = 0; kk < 4; kk++) q[kk] = *(const short4v*)(qp + kk * 16);
  }

  float m = -1e30f, lsum = 0.f;
  float4v o[4];
  #pragma unroll
  for (int fc = 0; fc < 4; fc++) { float4v z = {0.f,0.f,0.f,0.f}; o[fc] = z; }

  int krow = tid >> 2, kc = (tid & 3) << 4;
  int vr = (tid >> 3) << 1, vc = (tid & 7) << 3;
  const __hip_bfloat16* kbase = kqv + h * HD;
  const __hip_bfloat16* vbase = kqv + 2 * D_EMB + h * HD;

  short8v kA, kB, vA, vB;
  {
    const __hip_bfloat16* kp = kbase + (size_t)krow * DQKV + kc;
    kA = *(const short8v*)kp;
    kB = *(const short8v*)(kp + 8);
    const __hip_bfloat16* vp = vbase + (size_t)vr * DQKV + vc;
    vA = *(const short8v*)vp;
    vB = *(const short8v*)(vp + DQKV);
  }

  for (int kb = 0; kb <= qb; kb++) {
    __syncthreads();
    *(short8v*)(&Ksm[krow][kc])     = kA;
    *(short8v*)(&Ksm[krow][kc + 8]) = kB;
    #pragma unroll
    for (int j = 0; j < 8; j++) {
      unsigned int pk = (unsigned int)(unsigned short)vA[j]
                      | ((unsigned int)(unsigned short)vB[j] << 16);
      *reinterpret_cast<unsigned int*>(&Vtsm[vc + j][vr]) = pk;
    }
    __syncthreads();

    if (kb < qb) {
      const __hip_bfloat16* kp = kbase + (size_t)((kb + 1) * 64 + krow) * DQKV + kc;
      kA = *(const short8v*)kp;
      kB = *(const short8v*)(kp + 8);
      const __hip_bfloat16* vp = vbase + (size_t)((kb + 1) * 64 + vr) * DQKV + vc;
      vA = *(const short8v*)vp;
      vB = *(const short8v*)(vp + DQKV);
    }

    float4v s[4];
    #pragma unroll
    for (int fc = 0; fc < 4; fc++) { float4v z = {0.f,0.f,0.f,0.f}; s[fc] = z; }
    #pragma unroll
    for (int kk = 0; kk < 4; kk++) {
      #pragma unroll
      for (int fc = 0; fc < 4; fc++) {
        short4v kf = *(const short4v*)(&Ksm[fc * 16 + li][kk * 16 + 4 * lg]);
        s[fc] = mfma16(kf, q[kk], s[fc]);
      }
    }

    bool diag = (kb == qb);
    float pmax = -1e30f;
    #pragma unroll
    for (int fc = 0; fc < 4; fc++) {
      #pragma unroll
      for (int r = 0; r < 4; r++) {
        float v = s[fc][r] * 0.125f;
        if (diag && (fc * 16 + 4 * lg + r) > (w * 16 + li)) v = -1e30f;
        s[fc][r] = v;
        pmax = fmaxf(pmax, v);
      }
    }
    pmax = fmaxf(pmax, __shfl_xor(pmax, 16));
    pmax = fmaxf(pmax, __shfl_xor(pmax, 32));
    float mn = fmaxf(m, pmax);
    float alpha = __expf(m - mn);
    float rs = 0.f;
    #pragma unroll
    for (int fc = 0; fc < 4; fc++) {
      #pragma unroll
      for (int r = 0; r < 4; r++) {
        float p = __expf(s[fc][r] - mn);
        s[fc][r] = p;
        rs += p;
      }
    }
    rs += __shfl_xor(rs, 16);
    rs += __shfl_xor(rs, 32);
    lsum = lsum * alpha + rs;
    m = mn;
    #pragma unroll
    for (int fc = 0; fc < 4; fc++) {
      #pragma unroll
      for (int r = 0; r < 4; r++) o[fc][r] *= alpha;
    }

    short4v pb[4];
    #pragma unroll
    for (int kk = 0; kk < 4; kk++) {
      short4v t;
      #pragma unroll
      for (int r = 0; r < 4; r++) t[r] = bf16bits(s[kk][r]);
      pb[kk] = t;
    }

    #pragma unroll
    for (int kk = 0; kk < 4; kk++) {
      #pragma unroll
      for (int fc = 0; fc < 4; fc++) {
        short4v vf = *(const short4v*)(&Vtsm[fc * 16 + li][kk * 16 + 4 * lg]);
        o[fc] = mfma16(vf, pb[kk], o[fc]);
      }
    }
  }

  float inv = 1.0f / lsum;
  int qrow = qb * 64 + w * 16 + li;
  #pragma unroll
  for (int fc = 0; fc < 4; fc++) {
    short4v ov;
    #pragma unroll
    for (int r = 0; r < 4; r++) ov[r] = bf16bits(o[fc][r] * inv);
    *reinterpret_cast<short4v*>(y + (size_t)qrow * D_EMB + h * HD + fc * 16 + 4 * lg) = ov;
  }
}

// ---------------- launch ----------------
extern "C" void kernel_launch(void* const* d_in, const int* in_sizes, int n_in,
                              void* d_out, int out_size, void* d_ws, size_t ws_size,
                              hipStream_t stream)
{
  const float* x      = (const float*)d_in[0];
  const float* w_qkv  = (const float*)d_in[1];
  const float* b_qkv  = (const float*)d_in[2];
  const float* w_proj = (const float*)d_in[3];
  const float* b_proj = (const float*)d_in[4];
  const float* w_fc1  = (const float*)d_in[5];
  const float* b_fc1  = (const float*)d_in[6];
  const float* w_fc2  = (const float*)d_in[7];
  const float* b_fc2  = (const float*)d_in[8];
  const float* ln1_g  = (const float*)d_in[9];
  const float* ln1_b  = (const float*)d_in[10];
  const float* ln2_g  = (const float*)d_in[11];
  const float* ln2_b  = (const float*)d_in[12];

  char* ws = (char*)d_ws;
  size_t off = 0;
  __hip_bfloat16* wqkvT = (__hip_bfloat16*)(ws + off); off += (size_t)DQKV * D_EMB * 2;
  __hip_bfloat16* wprojT= (__hip_bfloat16*)(ws + off); off += (size_t)D_EMB * D_EMB * 2;
  __hip_bfloat16* wfc1T = (__hip_bfloat16*)(ws + off); off += (size_t)DFF * D_EMB * 2;
  __hip_bfloat16* wfc2T = (__hip_bfloat16*)(ws + off); off += (size_t)D_EMB * DFF * 2;
  __hip_bfloat16* lnbuf = (__hip_bfloat16*)(ws + off); off += (size_t)S_LEN * D_EMB * 2;
  __hip_bfloat16* kqv   = (__hip_bfloat16*)(ws + off);
  __hip_bfloat16* hbuf  = kqv;                         off += (size_t)S_LEN * DQKV * 2;
  __hip_bfloat16* ybuf  = (__hip_bfloat16*)(ws + off); off += (size_t)S_LEN * D_EMB * 2;
  float*          x1    = (float*)(ws + off);          off += (size_t)S_LEN * D_EMB * 4;
  (void)ws_size; (void)in_sizes; (void)n_in; (void)out_size;

  transpose_bf16_kernel<<<dim3((DQKV/32)*(D_EMB/32)), dim3(256), 0, stream>>>(w_qkv,  wqkvT, D_EMB, DQKV);
  transpose_bf16_kernel<<<dim3((D_EMB/32)*(D_EMB/32)), dim3(256), 0, stream>>>(w_proj, wprojT, D_EMB, D_EMB);
  transpose_bf16_kernel<<<dim3((DFF/32)*(D_EMB/32)),   dim3(256), 0, stream>>>(w_fc1,  wfc1T, D_EMB, DFF);
  transpose_bf16_kernel<<<dim3((D_EMB/32)*(DFF/32)),   dim3(256), 0, stream>>>(w_fc2,  wfc2T, DFF, D_EMB);

  ln_kernel<<<dim3(S_LEN), dim3(256), 0, stream>>>(x, ln1_g, ln1_b, lnbuf);
  gemm_kernel<0><<<dim3((DQKV/128)*(S_LEN/128)), dim3(256), 0, stream>>>(
      lnbuf, wqkvT, b_qkv, nullptr, kqv, S_LEN, DQKV, D_EMB);
  attn_kernel<<<dim3(NH * (S_LEN/64)), dim3(256), 0, stream>>>(kqv, ybuf);
  gemm_kernel<2><<<dim3((D_EMB/128)*(S_LEN/128)), dim3(256), 0, stream>>>(
      ybuf, wprojT, b_proj, x, x1, S_LEN, D_EMB, D_EMB);
  ln_kernel<<<dim3(S_LEN), dim3(256), 0, stream>>>(x1, ln2_g, ln2_b, lnbuf);
  gemm_kernel<1><<<dim3((DFF/128)*(S_LEN/128)), dim3(256), 0, stream>>>(
      lnbuf, wfc1T, b_fc1, nullptr, hbuf, S_LEN, DFF, D_EMB);
  gemm_kernel<2><<<dim3((D_EMB/128)*(S_LEN/128)), dim3(256), 0, stream>>>(
      hbuf, wfc2T, b_fc2, x1, (float*)d_out, S_LEN, D_EMB, DFF);
}